// Round 5
// baseline (363.688 us; speedup 1.0000x reference)
//
#include <hip/hip_runtime.h>

#define LQ 8500

typedef _Float16 half8 __attribute__((ext_vector_type(8)));
typedef _Float16 h2 __attribute__((ext_vector_type(2)));
typedef float f32x4 __attribute__((ext_vector_type(4)));

__device__ __forceinline__ unsigned short f2h(float f) {
    return __builtin_bit_cast(unsigned short, (_Float16)f);
}
__device__ __forceinline__ float hlo(unsigned w) {
    return (float)__builtin_bit_cast(_Float16, (unsigned short)(w & 0xffffu));
}
__device__ __forceinline__ float hhi(unsigned w) {
    return (float)__builtin_bit_cast(_Float16, (unsigned short)(w >> 16));
}
__device__ __forceinline__ unsigned pk2(float a, float b) {
    return (unsigned)f2h(a) | ((unsigned)f2h(b) << 16);
}
__device__ __forceinline__ h2 toh2(unsigned w) { return __builtin_bit_cast(h2, w); }

// ---------------------------------------------------------------------------
// Kernel 0: weight prep. Wct[384][256] = [Woff|Watt]^T fp16, Wvt = Wval^T fp16,
// Wot = Wout^T fp16, bcat[384] fp32.
// ---------------------------------------------------------------------------
__global__ __launch_bounds__(256) void prep_weights(const float* __restrict__ Woff,
                                                    const float* __restrict__ boff,
                                                    const float* __restrict__ Watt,
                                                    const float* __restrict__ batt,
                                                    const float* __restrict__ Wval,
                                                    const float* __restrict__ Wout,
                                                    unsigned short* __restrict__ Wct,
                                                    unsigned short* __restrict__ Wvt,
                                                    unsigned short* __restrict__ Wot,
                                                    float* __restrict__ bcat) {
    int idx = blockIdx.x * 256 + threadIdx.x;
    if (idx < 98304) {                       // Wct[j][k] = Wcat[k][j]
        int j = idx >> 8, k = idx & 255;
        float v = (j < 256) ? Woff[k * 256 + j] : Watt[k * 128 + (j - 256)];
        Wct[idx] = f2h(v);
    } else if (idx < 98304 + 65536) {        // Wvt[n][k] = Wval[k][n]
        int t = idx - 98304;
        int n = t >> 8, k = t & 255;
        Wvt[t] = f2h(Wval[k * 256 + n]);
    } else if (idx < 98304 + 131072) {       // Wot[n][k] = Wout[k][n]
        int t = idx - 98304 - 65536;
        int n = t >> 8, k = t & 255;
        Wot[t] = f2h(Wout[k * 256 + n]);
    } else if (idx < 98304 + 131072 + 384) {
        int j = idx - 98304 - 131072;
        bcat[j] = (j < 256) ? boff[j] : batt[j - 256];
    }
}

// ---------------------------------------------------------------------------
// Kernel 1: frame sums -> fp16 Xs. 8 channels/thread.
// ---------------------------------------------------------------------------
__global__ __launch_bounds__(256) void sum_frames(const float4* __restrict__ inp,
                                                  uint4* __restrict__ Xs) {
    int g = blockIdx.y;               // n*4 + t1
    int t1 = g & 3, n = g >> 2;
    int f = blockIdx.x * 256 + threadIdx.x;      // 8-elem chunk index
    if (f >= LQ * 32) return;
    int t2a = t1 == 0 ? 0 : t1 - 1;
    int t2b = t1 == 3 ? 3 : t1 + 1;
    float4 s0 = {0, 0, 0, 0}, s1 = {0, 0, 0, 0};
    for (int t2 = t2a; t2 <= t2b; ++t2) {
        const float4* p = inp + (size_t)(n * 4 + t2) * (LQ * 64) + (size_t)f * 2;
        float4 a = p[0], b = p[1];
        s0.x += a.x; s0.y += a.y; s0.z += a.z; s0.w += a.w;
        s1.x += b.x; s1.y += b.y; s1.z += b.z; s1.w += b.w;
    }
    uint4 o;
    o.x = pk2(s0.x, s0.y); o.y = pk2(s0.z, s0.w);
    o.z = pk2(s1.x, s1.y); o.w = pk2(s1.z, s1.w);
    Xs[(size_t)g * (LQ * 32) + f] = o;
}

// ---------------------------------------------------------------------------
// MFMA fp16 GEMM: C[M x N] = A[M x 256] @ Bt[N x 256]^T + bias.
// 128x128 tile, BK=32, 256 threads = 4 waves (2x2, each 64x64 = 4x4 frags).
// AF32: A is fp32 (converted to fp16 during staging).
// OUTMODE 0: fp32 flat N=256 (+bias). 1: fp16 Vs-plane N=256 (+bias*K(t1)).
// 2: fp16 flat N=384 (+bias).
// ---------------------------------------------------------------------------
template <int OUTMODE, int AF32>
__global__ __launch_bounds__(256) void gemm_f16(const void* __restrict__ Avoid,
                                                const unsigned short* __restrict__ Bt,
                                                const float* __restrict__ bias,
                                                void* __restrict__ Cout, int M) {
    __shared__ char lds[16384];       // As 8KB @0, Bs 8KB @8192 (both [128][32] f16, swizzled)
    const int tid = threadIdx.x;
    const int r0 = blockIdx.x * 128, c0 = blockIdx.y * 128;
    const int wid = tid >> 6, lane = tid & 63;
    const int wr = (wid >> 1) * 64, wc = (wid & 1) * 64;

    f32x4 acc[4][4] = {};

    for (int k0 = 0; k0 < 256; k0 += 32) {
#pragma unroll
        for (int cc = 0; cc < 2; ++cc) {
            int ch = cc * 256 + tid;           // 0..511 chunk of 16B (8 fp16)
            int row = ch >> 2, seg = ch & 3;
            int byte = (row << 6) + (seg << 4);
            int swz = byte ^ ((row & 7) << 4);
            uint4 va = {0, 0, 0, 0};
            int ar = r0 + row;
            if (ar < M) {
                if (AF32) {
                    const float4* ap = reinterpret_cast<const float4*>(
                        (const float*)Avoid + (size_t)ar * 256 + k0 + seg * 8);
                    float4 a = ap[0], b = ap[1];
                    va.x = pk2(a.x, a.y); va.y = pk2(a.z, a.w);
                    va.z = pk2(b.x, b.y); va.w = pk2(b.z, b.w);
                } else {
                    va = *reinterpret_cast<const uint4*>(
                        (const unsigned short*)Avoid + (size_t)ar * 256 + k0 + seg * 8);
                }
            }
            *reinterpret_cast<uint4*>(lds + swz) = va;
            uint4 vb = *reinterpret_cast<const uint4*>(Bt + (size_t)(c0 + row) * 256 + k0 + seg * 8);
            *reinterpret_cast<uint4*>(lds + 8192 + swz) = vb;
        }
        __syncthreads();
        half8 af[4], bf[4];
#pragma unroll
        for (int i = 0; i < 4; ++i) {
            int rowA = wr + i * 16 + (lane & 15);
            int byteA = (rowA << 6) + ((lane >> 4) << 4);
            af[i] = *reinterpret_cast<const half8*>(lds + (byteA ^ ((rowA & 7) << 4)));
            int rowB = wc + i * 16 + (lane & 15);
            int byteB = (rowB << 6) + ((lane >> 4) << 4);
            bf[i] = *reinterpret_cast<const half8*>(lds + 8192 + (byteB ^ ((rowB & 7) << 4)));
        }
#pragma unroll
        for (int i = 0; i < 4; ++i)
#pragma unroll
            for (int j = 0; j < 4; ++j)
                acc[i][j] = __builtin_amdgcn_mfma_f32_16x16x32_f16(af[i], bf[j], acc[i][j], 0, 0, 0);
        __syncthreads();
    }

#pragma unroll
    for (int j = 0; j < 4; ++j) {
        int col = c0 + wc + j * 16 + (lane & 15);
        float bv = bias[col];
#pragma unroll
        for (int i = 0; i < 4; ++i) {
#pragma unroll
            for (int r = 0; r < 4; ++r) {
                int row = r0 + wr + i * 16 + (lane >> 4) * 4 + r;
                if (row >= M) continue;
                float v = acc[i][j][r];
                if (OUTMODE == 1) {
                    int g = row / LQ;
                    int pos = row - g * LQ;
                    int t1 = g & 3;
                    float sc = (t1 == 0 || t1 == 3) ? 2.f : 3.f;
                    v += bv * sc;
                    int m = col >> 5, c = col & 31;
                    ((unsigned short*)Cout)[((size_t)(g * 8 + m) * LQ + pos) * 32 + c] = f2h(v);
                } else if (OUTMODE == 2) {
                    ((unsigned short*)Cout)[(size_t)row * 384 + col] = f2h(v + bv);
                } else {
                    ((float*)Cout)[(size_t)row * 256 + col] = v + bv;
                }
            }
        }
    }
}

// ---------------------------------------------------------------------------
// Kernel 4: LDS-free sampler, packed-fp16 accumulation (v_pk_fma_f16).
// Thread = (q, m, half): 16 channels as 8 half2 accumulators.
// Block = 16 q x 8 m x 2 half of one group g (bid & 7 -> XCD/L2 affinity).
// ---------------------------------------------------------------------------
__global__ __launch_bounds__(256) void sample_kernel(const unsigned short* __restrict__ P,
                                                     const float* __restrict__ refp,
                                                     const unsigned short* __restrict__ Vs,
                                                     unsigned short* __restrict__ O16) {
    int tid = threadIdx.x, bid = blockIdx.x;
    int g = bid & 7;
    int q0 = (bid >> 3) * 16;
    int ql = tid >> 4, m = (tid >> 1) & 7, h = tid & 1;
    int q = q0 + ql;
    if (q >= LQ) return;

    const size_t qrow = (size_t)g * LQ + q;

    // offsets (32 fp16) + att logits (16 fp16)
    unsigned ow[16];
    {
        const uint4* po = reinterpret_cast<const uint4*>(P + qrow * 384 + m * 32);
        uint4 a = po[0], b = po[1], c = po[2], d = po[3];
        ow[0] = a.x; ow[1] = a.y; ow[2] = a.z; ow[3] = a.w;
        ow[4] = b.x; ow[5] = b.y; ow[6] = b.z; ow[7] = b.w;
        ow[8] = c.x; ow[9] = c.y; ow[10] = c.z; ow[11] = c.w;
        ow[12] = d.x; ow[13] = d.y; ow[14] = d.z; ow[15] = d.w;
    }
    float wgt[16];
    {
        const uint4* pa = reinterpret_cast<const uint4*>(P + qrow * 384 + 256 + m * 16);
        uint4 a = pa[0], b = pa[1];
        unsigned aw[8] = {a.x, a.y, a.z, a.w, b.x, b.y, b.z, b.w};
#pragma unroll
        for (int j = 0; j < 8; ++j) {
            wgt[j * 2 + 0] = hlo(aw[j]);
            wgt[j * 2 + 1] = hhi(aw[j]);
        }
        float mx = -1e30f;
#pragma unroll
        for (int j = 0; j < 16; ++j) mx = fmaxf(mx, wgt[j]);
        float s = 0.f;
#pragma unroll
        for (int j = 0; j < 16; ++j) { wgt[j] = __expf(wgt[j] - mx); s += wgt[j]; }
        int t1 = g & 3;
        float Kc = (t1 == 0 || t1 == 3) ? 2.f : 3.f;
        float inv = 1.f / (s * Kc);
#pragma unroll
        for (int j = 0; j < 16; ++j) wgt[j] *= inv;
    }

    float rx[4], ry[4];
    {
        const float4* rp = reinterpret_cast<const float4*>(refp + qrow * 8);
        float4 r0 = rp[0], r1 = rp[1];
        rx[0] = r0.x; ry[0] = r0.y; rx[1] = r0.z; ry[1] = r0.w;
        rx[2] = r1.x; ry[2] = r1.y; rx[3] = r1.z; ry[3] = r1.w;
    }

    h2 acc[8];
#pragma unroll
    for (int d = 0; d < 8; ++d) acc[d] = h2{(_Float16)0.f, (_Float16)0.f};

    const unsigned short* vplane = Vs + (size_t)(g * 8 + m) * (LQ * 32) + h * 16;

#pragma unroll
    for (int p = 0; p < 16; ++p) {
        const int l = p >> 2;
        const int Wl = 80 >> l;
        const int start = (l == 0) ? 0 : (l == 1) ? 6400 : (l == 2) ? 8000 : 8400;
        const float Wlf = (float)Wl;

        float x = fmaf(rx[l], Wlf, hlo(ow[p])) - 0.5f;
        float y = fmaf(ry[l], Wlf, hhi(ow[p])) - 0.5f;
        float w = wgt[p];

        float xf = floorf(x), yf = floorf(y);
        int x0 = (int)xf, y0 = (int)yf;
        float wx1 = x - xf, wy1 = y - yf;

        int xb = min(max(x0, 0), Wl - 2);
        float wl = (x0 == xb) ? 1.f - wx1 : ((x0 + 1 == xb) ? wx1 : 0.f);
        float wr = (x0 == xb) ? wx1 : ((x0 - 1 == xb) ? 1.f - wx1 : 0.f);

        int yc[2];
        float cw[2];
        yc[0] = min(max(y0, 0), Wl - 1);
        cw[0] = (y0 >= 0 && y0 < Wl) ? (1.f - wy1) * w : 0.f;
        int y1i = y0 + 1;
        yc[1] = min(max(y1i, 0), Wl - 1);
        cw[1] = (y1i >= 0 && y1i < Wl) ? wy1 * w : 0.f;

#pragma unroll
        for (int ryi = 0; ryi < 2; ++ryi) {
            float clf = cw[ryi] * wl, crf = cw[ryi] * wr;
            _Float16 clh = (_Float16)clf, crh = (_Float16)crf;
            h2 cl2 = {clh, clh}, cr2 = {crh, crh};
            const uint4* vp = reinterpret_cast<const uint4*>(
                vplane + (size_t)(start + yc[ryi] * Wl + xb) * 32);
            uint4 La = vp[0], Lb = vp[1];   // left pos, this half's 16 ch
            uint4 Ra = vp[4], Rb = vp[5];   // right pos (+32 ushort)
            acc[0] += cl2 * toh2(La.x) + cr2 * toh2(Ra.x);
            acc[1] += cl2 * toh2(La.y) + cr2 * toh2(Ra.y);
            acc[2] += cl2 * toh2(La.z) + cr2 * toh2(Ra.z);
            acc[3] += cl2 * toh2(La.w) + cr2 * toh2(Ra.w);
            acc[4] += cl2 * toh2(Lb.x) + cr2 * toh2(Rb.x);
            acc[5] += cl2 * toh2(Lb.y) + cr2 * toh2(Rb.y);
            acc[6] += cl2 * toh2(Lb.z) + cr2 * toh2(Rb.z);
            acc[7] += cl2 * toh2(Lb.w) + cr2 * toh2(Rb.w);
        }
    }

    unsigned short* op = O16 + qrow * 256 + m * 32 + h * 16;
    uint4 o0, o1;
    o0.x = __builtin_bit_cast(unsigned, acc[0]);
    o0.y = __builtin_bit_cast(unsigned, acc[1]);
    o0.z = __builtin_bit_cast(unsigned, acc[2]);
    o0.w = __builtin_bit_cast(unsigned, acc[3]);
    o1.x = __builtin_bit_cast(unsigned, acc[4]);
    o1.y = __builtin_bit_cast(unsigned, acc[5]);
    o1.z = __builtin_bit_cast(unsigned, acc[6]);
    o1.w = __builtin_bit_cast(unsigned, acc[7]);
    reinterpret_cast<uint4*>(op)[0] = o0;
    reinterpret_cast<uint4*>(op)[1] = o1;
}

// ---------------------------------------------------------------------------
extern "C" void kernel_launch(void* const* d_in, const int* in_sizes, int n_in,
                              void* d_out, int out_size, void* d_ws, size_t ws_size,
                              hipStream_t stream) {
    const float* query = (const float*)d_in[0];
    const float* refp  = (const float*)d_in[1];
    const float* inp   = (const float*)d_in[2];
    const float* Woff = (const float*)d_in[5];
    const float* boff = (const float*)d_in[6];
    const float* Watt = (const float*)d_in[7];
    const float* batt = (const float*)d_in[8];
    const float* Wval = (const float*)d_in[9];
    const float* bval = (const float*)d_in[10];
    const float* Wout = (const float*)d_in[11];
    const float* bout = (const float*)d_in[12];
    float* out = (float*)d_out;

    // workspace layout (bytes):
    //   Xs16 f16 [68000][256]          @ 0            (34,816,000)  -- later O16 alias
    //   Vs   f16 [64 planes][8500][32] @ 34,816,000   (34,816,000)
    //   P    f16 [68000][384]          @ 69,632,000   (52,224,000)
    //   Wct  f16 [384][256]            @ 121,856,000  (196,608)
    //   Wvt  f16 [256][256]            @ 122,052,608  (131,072)
    //   Wot  f16 [256][256]            @ 122,183,680  (131,072)
    //   bcat f32 [384]                 @ 122,314,752  (1,536)
    char* base = (char*)d_ws;
    unsigned short* Xs16 = (unsigned short*)base;
    unsigned short* Vs   = (unsigned short*)(base + 34816000);
    unsigned short* P    = (unsigned short*)(base + 69632000);
    unsigned short* Wct  = (unsigned short*)(base + 121856000);
    unsigned short* Wvt  = (unsigned short*)(base + 122052608);
    unsigned short* Wot  = (unsigned short*)(base + 122183680);
    float* bcat          = (float*)(base + 122314752);
    unsigned short* O16  = Xs16;                 // alias after value GEMM

    // 0) weight prep
    prep_weights<<<dim3(898), 256, 0, stream>>>(Woff, boff, Watt, batt, Wval, Wout,
                                                Wct, Wvt, Wot, bcat);

    // 1) Xs16 = fp16 frame sums
    sum_frames<<<dim3((LQ * 32 + 255) / 256, 8), 256, 0, stream>>>(
        (const float4*)inp, (uint4*)Xs16);

    // 2) Vs = f16( Xs16 @ Wval + K(t1)*bval ), plane layout
    gemm_f16<1, 0><<<dim3((8 * LQ + 127) / 128, 2), 256, 0, stream>>>(
        Xs16, Wvt, bval, Vs, 8 * LQ);

    // 3) P = f16( query(f32) @ Wcat + bcat )  -- A converted during staging
    gemm_f16<2, 1><<<dim3((8 * LQ + 127) / 128, 3), 256, 0, stream>>>(
        query, Wct, bcat, P, 8 * LQ);

    // 4) sampler -> O16 (aliases Xs16)
    sample_kernel<<<dim3(((LQ + 15) / 16) * 8), 256, 0, stream>>>(P, refp, Vs, O16);

    // 5) d_out = O16 @ Wout + bout (fp32)
    gemm_f16<0, 0><<<dim3((8 * LQ + 127) / 128, 2), 256, 0, stream>>>(
        O16, Wot, bout, out, 8 * LQ);
}

// Round 6
// 360.816 us; speedup vs baseline: 1.0080x; 1.0080x over previous
//
#include <hip/hip_runtime.h>

#define LQ 8500

typedef _Float16 half8 __attribute__((ext_vector_type(8)));
typedef float f32x4 __attribute__((ext_vector_type(4)));

__device__ __forceinline__ unsigned short f2h(float f) {
    return __builtin_bit_cast(unsigned short, (_Float16)f);
}
__device__ __forceinline__ float hlo(unsigned w) {
    return (float)__builtin_bit_cast(_Float16, (unsigned short)(w & 0xffffu));
}
__device__ __forceinline__ float hhi(unsigned w) {
    return (float)__builtin_bit_cast(_Float16, (unsigned short)(w >> 16));
}
__device__ __forceinline__ unsigned pk2(float a, float b) {
    return (unsigned)f2h(a) | ((unsigned)f2h(b) << 16);
}

// ---------------------------------------------------------------------------
// Kernel 0: weight prep. Wct[384][256] = [Woff|Watt]^T fp16, Wvt = Wval^T,
// Wot = Wout^T fp16, bcat[384] fp32.
// ---------------------------------------------------------------------------
__global__ __launch_bounds__(256) void prep_weights(const float* __restrict__ Woff,
                                                    const float* __restrict__ boff,
                                                    const float* __restrict__ Watt,
                                                    const float* __restrict__ batt,
                                                    const float* __restrict__ Wval,
                                                    const float* __restrict__ Wout,
                                                    unsigned short* __restrict__ Wct,
                                                    unsigned short* __restrict__ Wvt,
                                                    unsigned short* __restrict__ Wot,
                                                    float* __restrict__ bcat) {
    int idx = blockIdx.x * 256 + threadIdx.x;
    if (idx < 98304) {                       // Wct[j][k] = Wcat[k][j]
        int j = idx >> 8, k = idx & 255;
        float v = (j < 256) ? Woff[k * 256 + j] : Watt[k * 128 + (j - 256)];
        Wct[idx] = f2h(v);
    } else if (idx < 98304 + 65536) {        // Wvt[n][k] = Wval[k][n]
        int t = idx - 98304;
        int n = t >> 8, k = t & 255;
        Wvt[t] = f2h(Wval[k * 256 + n]);
    } else if (idx < 98304 + 131072) {       // Wot[n][k] = Wout[k][n]
        int t = idx - 98304 - 65536;
        int n = t >> 8, k = t & 255;
        Wot[t] = f2h(Wout[k * 256 + n]);
    } else if (idx < 98304 + 131072 + 384) {
        int j = idx - 98304 - 131072;
        bcat[j] = (j < 256) ? boff[j] : batt[j - 256];
    }
}

// ---------------------------------------------------------------------------
// MFMA fp16 GEMM, double-buffered: C[M x N] = A[M x 256] @ Bt[N x 256]^T + bias.
// 128x128 tile, BK=32, 256 threads = 4 waves (2x2, each 64x64 = 4x4 frags).
// ASRC 0: A fp16 flat. 1: A fp32 flat (convert in staging).
//      2: A = input_flatten fp32; row g*LQ+pos sums frames t2 in [t1-1,t1+1].
// OUTMODE 0: fp32 flat N=256 (+bias). 1: fp16 Vs-plane N=256 (+bias*K(t1)).
// 2: fp16 flat N=384 (+bias).
// ---------------------------------------------------------------------------
template <int OUTMODE, int ASRC>
__global__ __launch_bounds__(256) void gemm_f16(const void* __restrict__ Avoid,
                                                const unsigned short* __restrict__ Bt,
                                                const float* __restrict__ bias,
                                                void* __restrict__ Cout, int M) {
    __shared__ char lds[32768];   // buf b: A @ b*16384, B @ b*16384+8192
    const int tid = threadIdx.x;
    const int r0 = blockIdx.x * 128, c0 = blockIdx.y * 128;
    const int wid = tid >> 6, lane = tid & 63;
    const int wr = (wid >> 1) * 64, wc = (wid & 1) * 64;

    f32x4 acc[4][4] = {};
    uint4 ra[2], rb[2];

    // chunk ch = cc*256+tid : row = ch>>2 (tile row), seg = ch&3 (8-f16 segment)
#define LOADT(k0)                                                                      \
    {                                                                                  \
        _Pragma("unroll")                                                              \
        for (int cc = 0; cc < 2; ++cc) {                                               \
            int ch = cc * 256 + tid;                                                   \
            int row = ch >> 2, seg = ch & 3;                                           \
            uint4 va = {0, 0, 0, 0};                                                   \
            int ar = r0 + row;                                                         \
            if (ar < M) {                                                              \
                if (ASRC == 0) {                                                       \
                    va = *reinterpret_cast<const uint4*>(                              \
                        (const unsigned short*)Avoid + (size_t)ar * 256 + (k0) + seg * 8); \
                } else if (ASRC == 1) {                                                \
                    const float4* ap = reinterpret_cast<const float4*>(                \
                        (const float*)Avoid + (size_t)ar * 256 + (k0) + seg * 8);      \
                    float4 a = ap[0], b = ap[1];                                       \
                    va.x = pk2(a.x, a.y); va.y = pk2(a.z, a.w);                        \
                    va.z = pk2(b.x, b.y); va.w = pk2(b.z, b.w);                        \
                } else {                                                               \
                    int g = ar / LQ;                                                   \
                    int pos = ar - g * LQ;                                             \
                    int t1 = g & 3, n = g >> 2;                                        \
                    int t2a = t1 == 0 ? 0 : t1 - 1;                                    \
                    int t2b = t1 == 3 ? 3 : t1 + 1;                                    \
                    float4 s0 = {0, 0, 0, 0}, s1 = {0, 0, 0, 0};                       \
                    for (int t2 = t2a; t2 <= t2b; ++t2) {                              \
                        const float4* p = reinterpret_cast<const float4*>(             \
                            (const float*)Avoid +                                      \
                            ((size_t)(n * 4 + t2) * LQ + pos) * 256 + (k0) + seg * 8); \
                        float4 a = p[0], b = p[1];                                     \
                        s0.x += a.x; s0.y += a.y; s0.z += a.z; s0.w += a.w;            \
                        s1.x += b.x; s1.y += b.y; s1.z += b.z; s1.w += b.w;            \
                    }                                                                  \
                    va.x = pk2(s0.x, s0.y); va.y = pk2(s0.z, s0.w);                    \
                    va.z = pk2(s1.x, s1.y); va.w = pk2(s1.z, s1.w);                    \
                }                                                                      \
            }                                                                          \
            ra[cc] = va;                                                               \
            rb[cc] = *reinterpret_cast<const uint4*>(Bt + (size_t)(c0 + row) * 256 +   \
                                                     (k0) + seg * 8);                  \
        }                                                                              \
    }

#define STORET(b)                                                                      \
    {                                                                                  \
        _Pragma("unroll")                                                              \
        for (int cc = 0; cc < 2; ++cc) {                                               \
            int ch = cc * 256 + tid;                                                   \
            int row = ch >> 2, seg = ch & 3;                                           \
            int byte = (row << 6) + (seg << 4);                                        \
            int swz = byte ^ ((row & 7) << 4);                                         \
            *reinterpret_cast<uint4*>(lds + (b) * 16384 + swz) = ra[cc];               \
            *reinterpret_cast<uint4*>(lds + (b) * 16384 + 8192 + swz) = rb[cc];        \
        }                                                                              \
    }

    LOADT(0);
    STORET(0);
    __syncthreads();

    for (int t = 0; t < 8; ++t) {
        if (t < 7) LOADT((t + 1) * 32);
        char* base = lds + (t & 1) * 16384;
        half8 af[4], bf[4];
#pragma unroll
        for (int i = 0; i < 4; ++i) {
            int rowA = wr + i * 16 + (lane & 15);
            int byteA = (rowA << 6) + ((lane >> 4) << 4);
            af[i] = *reinterpret_cast<const half8*>(base + (byteA ^ ((rowA & 7) << 4)));
            int rowB = wc + i * 16 + (lane & 15);
            int byteB = (rowB << 6) + ((lane >> 4) << 4);
            bf[i] = *reinterpret_cast<const half8*>(base + 8192 + (byteB ^ ((rowB & 7) << 4)));
        }
#pragma unroll
        for (int i = 0; i < 4; ++i)
#pragma unroll
            for (int j = 0; j < 4; ++j)
                acc[i][j] = __builtin_amdgcn_mfma_f32_16x16x32_f16(af[i], bf[j], acc[i][j], 0, 0, 0);
        if (t < 7) STORET((t + 1) & 1);
        __syncthreads();
    }

#pragma unroll
    for (int j = 0; j < 4; ++j) {
        int col = c0 + wc + j * 16 + (lane & 15);
        float bv = bias[col];
#pragma unroll
        for (int i = 0; i < 4; ++i) {
#pragma unroll
            for (int r = 0; r < 4; ++r) {
                int row = r0 + wr + i * 16 + (lane >> 4) * 4 + r;
                if (row >= M) continue;
                float v = acc[i][j][r];
                if (OUTMODE == 1) {
                    int g = row / LQ;
                    int pos = row - g * LQ;
                    int t1 = g & 3;
                    float sc = (t1 == 0 || t1 == 3) ? 2.f : 3.f;
                    v += bv * sc;
                    int m = col >> 5, c = col & 31;
                    ((unsigned short*)Cout)[((size_t)(g * 8 + m) * LQ + pos) * 32 + c] = f2h(v);
                } else if (OUTMODE == 2) {
                    ((unsigned short*)Cout)[(size_t)row * 384 + col] = f2h(v + bv);
                } else {
                    ((float*)Cout)[(size_t)row * 256 + col] = v + bv;
                }
            }
        }
    }
#undef LOADT
#undef STORET
}

// ---------------------------------------------------------------------------
// Sampler: fp32 accumulation, all 8 gather loads per point batched for MLP.
// Thread = (q, m, half): 16 channels. Block = 16 q x 8 m x 2 half of group g.
// ---------------------------------------------------------------------------
__global__ __launch_bounds__(256) void sample_kernel(const unsigned short* __restrict__ P,
                                                     const float* __restrict__ refp,
                                                     const unsigned short* __restrict__ Vs,
                                                     unsigned short* __restrict__ O16) {
    int tid = threadIdx.x, bid = blockIdx.x;
    int g = bid & 7;
    int q0 = (bid >> 3) * 16;
    int ql = tid >> 4, m = (tid >> 1) & 7, h = tid & 1;
    int q = q0 + ql;
    if (q >= LQ) return;

    const size_t qrow = (size_t)g * LQ + q;

    // offsets (32 fp16) + att logits (16 fp16)
    unsigned ow[16];
    {
        const uint4* po = reinterpret_cast<const uint4*>(P + qrow * 384 + m * 32);
        uint4 a = po[0], b = po[1], c = po[2], d = po[3];
        ow[0] = a.x; ow[1] = a.y; ow[2] = a.z; ow[3] = a.w;
        ow[4] = b.x; ow[5] = b.y; ow[6] = b.z; ow[7] = b.w;
        ow[8] = c.x; ow[9] = c.y; ow[10] = c.z; ow[11] = c.w;
        ow[12] = d.x; ow[13] = d.y; ow[14] = d.z; ow[15] = d.w;
    }
    float wgt[16];
    {
        const uint4* pa = reinterpret_cast<const uint4*>(P + qrow * 384 + 256 + m * 16);
        uint4 a = pa[0], b = pa[1];
        unsigned aw[8] = {a.x, a.y, a.z, a.w, b.x, b.y, b.z, b.w};
#pragma unroll
        for (int j = 0; j < 8; ++j) {
            wgt[j * 2 + 0] = hlo(aw[j]);
            wgt[j * 2 + 1] = hhi(aw[j]);
        }
        float mx = -1e30f;
#pragma unroll
        for (int j = 0; j < 16; ++j) mx = fmaxf(mx, wgt[j]);
        float s = 0.f;
#pragma unroll
        for (int j = 0; j < 16; ++j) { wgt[j] = __expf(wgt[j] - mx); s += wgt[j]; }
        int t1 = g & 3;
        float Kc = (t1 == 0 || t1 == 3) ? 2.f : 3.f;
        float inv = 1.f / (s * Kc);
#pragma unroll
        for (int j = 0; j < 16; ++j) wgt[j] *= inv;
    }

    float rx[4], ry[4];
    {
        const float4* rp = reinterpret_cast<const float4*>(refp + qrow * 8);
        float4 r0 = rp[0], r1 = rp[1];
        rx[0] = r0.x; ry[0] = r0.y; rx[1] = r0.z; ry[1] = r0.w;
        rx[2] = r1.x; ry[2] = r1.y; rx[3] = r1.z; ry[3] = r1.w;
    }

    float acc[16];
#pragma unroll
    for (int d = 0; d < 16; ++d) acc[d] = 0.f;

    const unsigned short* vplane = Vs + (size_t)(g * 8 + m) * (LQ * 32) + h * 16;

#pragma unroll 4
    for (int p = 0; p < 16; ++p) {
        const int l = p >> 2;
        const int Wl = 80 >> l;
        const int start = (l == 0) ? 0 : (l == 1) ? 6400 : (l == 2) ? 8000 : 8400;
        const float Wlf = (float)Wl;

        float x = fmaf(rx[l], Wlf, hlo(ow[p])) - 0.5f;
        float y = fmaf(ry[l], Wlf, hhi(ow[p])) - 0.5f;
        float w = wgt[p];

        float xf = floorf(x), yf = floorf(y);
        int x0 = (int)xf, y0 = (int)yf;
        float wx1 = x - xf, wy1 = y - yf;

        int xb = min(max(x0, 0), Wl - 2);
        float wl = (x0 == xb) ? 1.f - wx1 : ((x0 + 1 == xb) ? wx1 : 0.f);
        float wr = (x0 == xb) ? wx1 : ((x0 - 1 == xb) ? 1.f - wx1 : 0.f);

        int yc0 = min(max(y0, 0), Wl - 1);
        float cw0 = (y0 >= 0 && y0 < Wl) ? (1.f - wy1) * w : 0.f;
        int y1i = y0 + 1;
        int yc1 = min(max(y1i, 0), Wl - 1);
        float cw1 = (y1i >= 0 && y1i < Wl) ? wy1 * w : 0.f;

        // batch all 8 loads (2 rows x L/R x 2 uint4)
        const uint4* p0 = reinterpret_cast<const uint4*>(
            vplane + (size_t)(start + yc0 * Wl + xb) * 32);
        const uint4* p1 = reinterpret_cast<const uint4*>(
            vplane + (size_t)(start + yc1 * Wl + xb) * 32);
        uint4 L0a = p0[0], L0b = p0[1], R0a = p0[4], R0b = p0[5];
        uint4 L1a = p1[0], L1b = p1[1], R1a = p1[4], R1b = p1[5];

        float c0l = cw0 * wl, c0r = cw0 * wr;
        float c1l = cw1 * wl, c1r = cw1 * wr;

        acc[0]  += c0l * hlo(L0a.x) + c0r * hlo(R0a.x) + c1l * hlo(L1a.x) + c1r * hlo(R1a.x);
        acc[1]  += c0l * hhi(L0a.x) + c0r * hhi(R0a.x) + c1l * hhi(L1a.x) + c1r * hhi(R1a.x);
        acc[2]  += c0l * hlo(L0a.y) + c0r * hlo(R0a.y) + c1l * hlo(L1a.y) + c1r * hlo(R1a.y);
        acc[3]  += c0l * hhi(L0a.y) + c0r * hhi(R0a.y) + c1l * hhi(L1a.y) + c1r * hhi(R1a.y);
        acc[4]  += c0l * hlo(L0a.z) + c0r * hlo(R0a.z) + c1l * hlo(L1a.z) + c1r * hlo(R1a.z);
        acc[5]  += c0l * hhi(L0a.z) + c0r * hhi(R0a.z) + c1l * hhi(L1a.z) + c1r * hhi(R1a.z);
        acc[6]  += c0l * hlo(L0a.w) + c0r * hlo(R0a.w) + c1l * hlo(L1a.w) + c1r * hlo(R1a.w);
        acc[7]  += c0l * hhi(L0a.w) + c0r * hhi(R0a.w) + c1l * hhi(L1a.w) + c1r * hhi(R1a.w);
        acc[8]  += c0l * hlo(L0b.x) + c0r * hlo(R0b.x) + c1l * hlo(L1b.x) + c1r * hlo(R1b.x);
        acc[9]  += c0l * hhi(L0b.x) + c0r * hhi(R0b.x) + c1l * hhi(L1b.x) + c1r * hhi(R1b.x);
        acc[10] += c0l * hlo(L0b.y) + c0r * hlo(R0b.y) + c1l * hlo(L1b.y) + c1r * hlo(R1b.y);
        acc[11] += c0l * hhi(L0b.y) + c0r * hhi(R0b.y) + c1l * hhi(L1b.y) + c1r * hhi(R1b.y);
        acc[12] += c0l * hlo(L0b.z) + c0r * hlo(R0b.z) + c1l * hlo(L1b.z) + c1r * hlo(R1b.z);
        acc[13] += c0l * hhi(L0b.z) + c0r * hhi(R0b.z) + c1l * hhi(L1b.z) + c1r * hhi(R1b.z);
        acc[14] += c0l * hlo(L0b.w) + c0r * hlo(R0b.w) + c1l * hlo(L1b.w) + c1r * hlo(R1b.w);
        acc[15] += c0l * hhi(L0b.w) + c0r * hhi(R0b.w) + c1l * hhi(L1b.w) + c1r * hhi(R1b.w);
    }

    unsigned short* op = O16 + qrow * 256 + m * 32 + h * 16;
    uint4 o0, o1;
    o0.x = pk2(acc[0], acc[1]);   o0.y = pk2(acc[2], acc[3]);
    o0.z = pk2(acc[4], acc[5]);   o0.w = pk2(acc[6], acc[7]);
    o1.x = pk2(acc[8], acc[9]);   o1.y = pk2(acc[10], acc[11]);
    o1.z = pk2(acc[12], acc[13]); o1.w = pk2(acc[14], acc[15]);
    reinterpret_cast<uint4*>(op)[0] = o0;
    reinterpret_cast<uint4*>(op)[1] = o1;
}

// ---------------------------------------------------------------------------
extern "C" void kernel_launch(void* const* d_in, const int* in_sizes, int n_in,
                              void* d_out, int out_size, void* d_ws, size_t ws_size,
                              hipStream_t stream) {
    const float* query = (const float*)d_in[0];
    const float* refp  = (const float*)d_in[1];
    const float* inp   = (const float*)d_in[2];
    const float* Woff = (const float*)d_in[5];
    const float* boff = (const float*)d_in[6];
    const float* Watt = (const float*)d_in[7];
    const float* batt = (const float*)d_in[8];
    const float* Wval = (const float*)d_in[9];
    const float* bval = (const float*)d_in[10];
    const float* Wout = (const float*)d_in[11];
    const float* bout = (const float*)d_in[12];
    float* out = (float*)d_out;

    // workspace layout (bytes):
    //   Vs   f16 [64 planes][8500][32] @ 0            (34,816,000)
    //   P    f16 [68000][384]          @ 34,816,000   (52,224,000)
    //   O16  f16 [68000][256]          @ 87,040,000   (34,816,000)
    //   Wct  f16 [384][256]            @ 121,856,000  (196,608)
    //   Wvt  f16 [256][256]            @ 122,052,608  (131,072)
    //   Wot  f16 [256][256]            @ 122,183,680  (131,072)
    //   bcat f32 [384]                 @ 122,314,752  (1,536)
    char* base = (char*)d_ws;
    unsigned short* Vs   = (unsigned short*)base;
    unsigned short* P    = (unsigned short*)(base + 34816000);
    unsigned short* O16  = (unsigned short*)(base + 87040000);
    unsigned short* Wct  = (unsigned short*)(base + 121856000);
    unsigned short* Wvt  = (unsigned short*)(base + 122052608);
    unsigned short* Wot  = (unsigned short*)(base + 122183680);
    float* bcat          = (float*)(base + 122314752);

    // 0) weight prep
    prep_weights<<<dim3(898), 256, 0, stream>>>(Woff, boff, Watt, batt, Wval, Wout,
                                                Wct, Wvt, Wot, bcat);

    // 1) Vs = f16( framesum(input) @ Wval + K(t1)*bval ), plane layout (fused sum)
    gemm_f16<1, 2><<<dim3((8 * LQ + 127) / 128, 2), 256, 0, stream>>>(
        inp, Wvt, bval, Vs, 8 * LQ);

    // 2) P = f16( query(f32) @ Wcat + bcat )
    gemm_f16<2, 1><<<dim3((8 * LQ + 127) / 128, 3), 256, 0, stream>>>(
        query, Wct, bcat, P, 8 * LQ);

    // 3) sampler -> O16
    sample_kernel<<<dim3(((LQ + 15) / 16) * 8), 256, 0, stream>>>(P, refp, Vs, O16);

    // 4) d_out = O16 @ Wout + bout (fp32)
    gemm_f16<0, 0><<<dim3((8 * LQ + 127) / 128, 2), 256, 0, stream>>>(
        O16, Wot, bout, out, 8 * LQ);
}